// Round 9
// baseline (213.632 us; speedup 1.0000x reference)
//
#include <hip/hip_runtime.h>
#include <hip/hip_bf16.h>

typedef unsigned short u16;
typedef __attribute__((ext_vector_type(8))) short short8;
typedef __attribute__((ext_vector_type(8))) unsigned short ushort8;
typedef __attribute__((ext_vector_type(4))) float f32x4;
typedef __attribute__((ext_vector_type(4))) float f4;

#define GLB_CAST(p) ((const __attribute__((address_space(1))) unsigned int*)(p))
#define LDS_CAST(p) ((__attribute__((address_space(3))) unsigned int*)(p))

__device__ __forceinline__ void gl_lds16(const void* g, void* l) {
  __builtin_amdgcn_global_load_lds(GLB_CAST(g), LDS_CAST(l), 16, 0, 0);
}

__device__ __forceinline__ u16 f2bf(float f) {
  __hip_bfloat16 b = __float2bfloat16(f);           // RNE
  return __builtin_bit_cast(u16, b);
}

// ---------------- prep: W [R][C] f32 -> Wt [C][R] bf16 ----------------
__global__ void transpose_cvt_k(const float* __restrict__ in,
                                u16* __restrict__ out, int R, int C) {
  __shared__ float tile[32][33];
  int c0 = blockIdx.x * 32, r0 = blockIdx.y * 32;
  int tx = threadIdx.x, ty = threadIdx.y;     // 32 x 8
#pragma unroll
  for (int i = 0; i < 32; i += 8)
    tile[ty + i][tx] = in[(size_t)(r0 + ty + i) * C + c0 + tx];
  __syncthreads();
#pragma unroll
  for (int i = 0; i < 32; i += 8)
    out[(size_t)(c0 + ty + i) * R + r0 + tx] = f2bf(tile[tx][ty + i]);
}

// ========== Streaming GEMM, 64x64 wave tiles (32 FLOP per LDS byte) ==========
// EPI=1: qkv = x(f32)@w1T^T (+bias) -> q/k/v row-major [b,h,t,d] bf16; NT=9.
// EPI=2: out = att(bf16)@pT^T (+bias) -> f32 [M,384]; NT=3.
// Block 128 thr = 2 waves; wave tile 64m x 64n (acc[4][4]); block = 64 rows x full N.
// A [64x384] resident LDS (48KB). B: wave-private 3-slot ring (4KB slots, 4 gl_lds
// per stage), depth-2 prefetch, counted per-wave vmcnt, no barriers in loop.
// LDS 78336B -> 2 blocks/CU.
template <int EPI>
__global__ __launch_bounds__(128, 1) void gemm_k(
    const void* __restrict__ Av, const u16* __restrict__ Bt,
    const float* __restrict__ bias,
    u16* __restrict__ oQ, u16* __restrict__ oK, u16* __restrict__ oV,
    float* __restrict__ oF) {
  constexpr int K = 384;
  constexpr int NT = (EPI == 1) ? 9 : 3;
  __shared__ u16 As[64 * 384];         // 48KB, swizzled rows of 768B
  __shared__ u16 Bs[2][3][2048];       // 24KB: per-wave 3 slots [64col][32k]
  __shared__ float bias_s[NT * 128];

  const int tid = threadIdx.x;
  const int m0 = blockIdx.x * 64;
  const int lane = tid & 63, wid = tid >> 6;   // 2 waves: wc = wid
  const int lo = lane & 15, hi = lane >> 4;
  const int wc = wid;

  for (int i = tid; i < NT * 128; i += 128) bias_s[i] = bias[i];

  // ---- B staging: slot [64col][32k], 64B rows; pos p holds chunk p^((col>>1)&3) ----
  // gl_lds j (j=0..3): col = j*16 + lane/4; source k-chunk = (lane&3)^((lane>>3)&3)
  const int bcolo = wc * 64 + (lane >> 2);                 // + j*16
  const int bko = ((lane & 3) ^ ((lane >> 3) & 3)) * 8;    // elems
  char* const slot_l = (char*)&Bs[0][0][0] + wid * 12288 + lane * 16;
  auto stageB = [&](int slot, int tn, int kt) {
    const u16* s = Bt + (size_t)(tn * 128 + bcolo) * K + kt * 32 + bko;
    char* d = slot_l + slot * 4096;
#pragma unroll
    for (int j = 0; j < 4; ++j)
      gl_lds16(s + (size_t)(j * 16) * K, d + j * 1024);
  };

  stageB(0, 0, 0);
  stageB(1, 0, 1);

  // ---- A staged once: rows of 768B, chunk q holds k-chunk q ^ (row&7) ----
  if (EPI == 1) {
    const float* X = (const float*)Av;
#pragma unroll
    for (int i = 0; i < 24; ++i) {
      int c = tid + i * 128;           // 3072 chunks of 16B
      int row = c / 48, cc = c % 48;
      const float* src = X + (size_t)(m0 + row) * K + cc * 8;
      f4 a = *(const f4*)src;
      f4 b = *(const f4*)(src + 4);
      ushort8 o;
#pragma unroll
      for (int j = 0; j < 4; ++j) { o[j] = f2bf(a[j]); o[4 + j] = f2bf(b[j]); }
      *(ushort8*)((char*)As + row * 768 + ((cc * 16) ^ ((row & 7) << 4))) = o;
    }
  } else {
    const u16* Ab = (const u16*)Av;
#pragma unroll
    for (int i = 0; i < 24; ++i) {
      int c = tid + i * 128;
      int row = c / 48, cc = c % 48;
      int cs = cc ^ (row & 7);
      gl_lds16(Ab + (size_t)(m0 + row) * K + cs * 8, (char*)As + c * 16);
    }
  }
  __syncthreads();    // full drain (A ready, prologue B slots 0/1 ready)

  const int akey = (lo & 7) << 4;
  const int rk = ((lo >> 1) & 3) << 4;       // B read key
  int abase[4];
#pragma unroll
  for (int m = 0; m < 4; ++m) abase[m] = (m * 16 + lo) * 768;
  const int bbase = lo * 64 + (hi * 16 ^ rk);     // + n*1024
  const char* const Asc = (const char*)As;
  const char* const sb0 = (const char*)&Bs[0][0][0] + wid * 12288;

  // epilogue per-thread row parts
  int rp[4][4];
#pragma unroll
  for (int m = 0; m < 4; ++m)
#pragma unroll
    for (int rr = 0; rr < 4; ++rr) {
      int gm = m0 + m * 16 + hi * 4 + rr;
      rp[m][rr] = (EPI == 1) ? ((gm >> 8) * 98304 + (gm & 255) * 64)  // b*6*16384 + t*64
                             : gm * 384;
    }

  const f32x4 Z4 = {0.f, 0.f, 0.f, 0.f};

  for (int t = 0; t < NT; ++t) {
    f32x4 acc[4][4];
#pragma unroll
    for (int m = 0; m < 4; ++m)
#pragma unroll
      for (int n = 0; n < 4; ++n) acc[m][n] = Z4;

#pragma unroll
    for (int kt = 0; kt < 12; ++kt) {
      // schedule (verified): steady vmcnt(4) retires slot kt, leaves kt+1 in flight;
      // kt==11 drains the last slot; kt==0 additionally drains prev-tile stores.
      if (kt == 11) asm volatile("s_waitcnt vmcnt(0)" ::: "memory");
      else          asm volatile("s_waitcnt vmcnt(4)" ::: "memory");

      const char* sb = sb0 + (kt % 3) * 4096;
      short8 af[4], bf[4];
#pragma unroll
      for (int m = 0; m < 4; ++m)
        af[m] = *(const short8*)(Asc + abase[m] + ((kt * 64 + hi * 16) ^ akey));
#pragma unroll
      for (int n = 0; n < 4; ++n)
        bf[n] = *(const short8*)(sb + n * 1024 + bbase);

      if (kt < 10) stageB((kt + 2) % 3, t, kt + 2);

      __builtin_amdgcn_s_setprio(1);
#pragma unroll
      for (int m = 0; m < 4; ++m)
#pragma unroll
        for (int n = 0; n < 4; ++n)
          acc[m][n] = __builtin_amdgcn_mfma_f32_16x16x32_bf16(af[m], bf[n], acc[m][n], 0, 0, 0);
      __builtin_amdgcn_s_setprio(0);
    }

    // ---- epilogue stores (before next-tile stages; drained at next kt=0) ----
    if (EPI == 1) {
      int r3 = t / 3;
      u16* dst = (r3 == 0) ? oQ : ((r3 == 1) ? oK : oV);
#pragma unroll
      for (int n = 0; n < 4; ++n) {
        int c = wc * 64 + n * 16 + lo;
        int hc = (t - r3 * 3) * 128 + c;
        int cp = ((hc >> 6) << 14) + (hc & 63);          // hh*16384 + d
        float bs = bias_s[t * 128 + c];
#pragma unroll
        for (int m = 0; m < 4; ++m)
#pragma unroll
          for (int rr = 0; rr < 4; ++rr)
            dst[(size_t)(rp[m][rr] + cp)] = f2bf(acc[m][n][rr] + bs);
      }
    } else {
#pragma unroll
      for (int n = 0; n < 4; ++n) {
        int col = t * 128 + wc * 64 + n * 16 + lo;
        float bs = bias_s[col];
#pragma unroll
        for (int m = 0; m < 4; ++m)
#pragma unroll
          for (int rr = 0; rr < 4; ++rr)
            oF[(size_t)(rp[m][rr] + col)] = acc[m][n][rr] + bs;
      }
    }

    if (t + 1 < NT) {      // next tile's slots 0,1 (issued after stores)
      stageB(0, t + 1, 0);
      stageB(1, t + 1, 1);
    }
  }
}

// ---------------- windowed causal attention (V row-major, transpose at staging) ----------------
__global__ __launch_bounds__(256) void attn_k(
    const u16* __restrict__ Qb, const u16* __restrict__ Kb,
    const u16* __restrict__ Vb, const float* __restrict__ gate,
    u16* __restrict__ Ao) {
  __shared__ u16 Ks[128 * 64];      // [key][d]   swizzled, 16KB
  __shared__ u16 Vs[64 * 128];      // [d][key]   swizzled, 16KB
  __shared__ u16 Ps[4][16 * 128];   // per-wave P [q][key] swizzled, 16KB
  const int bx = blockIdx.x;
  const int qt = bx & 3, bh = bx >> 2;
  const int h = bh % 6, b = bh / 6;
  const int i0 = qt * 64, j0 = i0 - 64;
  const int tid = threadIdx.x, w = tid >> 6, lane = tid & 63;
  const int lo = lane & 15, hi = lane >> 4;

  const u16* Kh = Kb + (size_t)bh * (256 * 64);
  const u16* Vh = Vb + (size_t)bh * (256 * 64);
  const u16* Qh = Qb + (size_t)bh * (256 * 64);

#pragma unroll
  for (int it = 0; it < 4; ++it) {
    int chunk = tid + it * 256;
    int row = chunk >> 3, cc = chunk & 7;
    int csrc = cc ^ (row & 7);
    int j = j0 + row; if (j < 0) j = 0;
    gl_lds16(Kh + j * 64 + csrc * 8, Ks + chunk * 8);
  }
#pragma unroll
  for (int it = 0; it < 4; ++it) {
    int c = tid + it * 256;
    int dc = c >> 7;
    int j = c & 127;
    int jj = j0 + j; if (jj < 0) jj = 0;
    ushort8 v = *(const ushort8*)(Vh + jj * 64 + dc * 8);
#pragma unroll
    for (int e = 0; e < 8; ++e) {
      int d = dc * 8 + e;
      *(u16*)((char*)Vs + ((d * 256 + 2 * j) ^ ((d & 7) << 4))) = v[e];
    }
  }

  const int iq = i0 + w * 16 + lo;
  short8 aq0 = *(const short8*)(Qh + iq * 64 + hi * 8);
  short8 aq1 = *(const short8*)(Qh + iq * 64 + 32 + hi * 8);

  __syncthreads();

  const f32x4 Z4 = {0.f, 0.f, 0.f, 0.f};
  f32x4 accS[8];
#pragma unroll
  for (int t = 0; t < 8; ++t) accS[t] = Z4;
#pragma unroll
  for (int t = 0; t < 8; ++t) {
    int key = t * 16 + lo;
    int base = key * 128;
    int sw = (key & 7) << 4;
    short8 bk0 = *(const short8*)((const char*)Ks + ((base + hi * 16) ^ sw));
    short8 bk1 = *(const short8*)((const char*)Ks + ((base + 64 + hi * 16) ^ sw));
    accS[t] = __builtin_amdgcn_mfma_f32_16x16x32_bf16(aq0, bk0, accS[t], 0, 0, 0);
    accS[t] = __builtin_amdgcn_mfma_f32_16x16x32_bf16(aq1, bk1, accS[t], 0, 0, 0);
  }

  float pv[4][8];
  float rinv[4];
#pragma unroll
  for (int r = 0; r < 4; ++r) {
    int i = i0 + w * 16 + hi * 4 + r;
    float mx = -1e30f;
    float vals[8];
#pragma unroll
    for (int t = 0; t < 8; ++t) {
      int j = j0 + t * 16 + lo;
      float s = accS[t][r] * 0.125f;
      bool ok = (j >= 0) && (j <= i) && (j >= i - 64);
      vals[t] = ok ? s : -1e30f;
      mx = fmaxf(mx, vals[t]);
    }
#pragma unroll
    for (int off = 1; off < 16; off <<= 1) mx = fmaxf(mx, __shfl_xor(mx, off));
    float sum = 0.f;
#pragma unroll
    for (int t = 0; t < 8; ++t) {
      float p = __expf(vals[t] - mx);
      pv[r][t] = p;
      sum += p;
    }
#pragma unroll
    for (int off = 1; off < 16; off <<= 1) sum += __shfl_xor(sum, off);
    rinv[r] = 1.0f / sum;
  }

  u16* Pw = Ps[w];
#pragma unroll
  for (int r = 0; r < 4; ++r) {
    int ql = hi * 4 + r;
    int sw = (ql & 7) << 4;
#pragma unroll
    for (int t = 0; t < 8; ++t) {
      int off = (ql * 256 + (t * 16 + lo) * 2) ^ sw;
      *(u16*)((char*)Pw + off) = f2bf(pv[r][t]);
    }
  }

  f32x4 accO[4];
#pragma unroll
  for (int dt = 0; dt < 4; ++dt) accO[dt] = Z4;
#pragma unroll
  for (int ks = 0; ks < 4; ++ks) {
    int offA = (lo * 256 + ks * 64 + hi * 16) ^ ((lo & 7) << 4);
    short8 ap = *(const short8*)((const char*)Pw + offA);
#pragma unroll
    for (int dt = 0; dt < 4; ++dt) {
      int d = dt * 16 + lo;
      int offB = (d * 256 + ks * 64 + hi * 16) ^ ((d & 7) << 4);
      short8 bv = *(const short8*)((const char*)Vs + offB);
      accO[dt] = __builtin_amdgcn_mfma_f32_16x16x32_bf16(ap, bv, accO[dt], 0, 0, 0);
    }
  }

#pragma unroll
  for (int dt = 0; dt < 4; ++dt) {
    int d = dt * 16 + lo;
    float gg = gate[h * 64 + d];
#pragma unroll
    for (int r = 0; r < 4; ++r) {
      int i = i0 + w * 16 + hi * 4 + r;
      float v = accO[dt][r] * rinv[r] * gg;
      Ao[(size_t)(b * 256 + i) * 384 + h * 64 + d] = f2bf(v);
    }
  }
}

// ---------------- launch ----------------
extern "C" void kernel_launch(void* const* d_in, const int* in_sizes, int n_in,
                              void* d_out, int out_size, void* d_ws, size_t ws_size,
                              hipStream_t stream) {
  const float* x      = (const float*)d_in[0];
  const float* qkv_w  = (const float*)d_in[1];
  const float* qkv_b  = (const float*)d_in[2];
  const float* proj_w = (const float*)d_in[3];
  const float* proj_b = (const float*)d_in[4];
  const float* gate   = (const float*)d_in[5];
  float* out = (float*)d_out;

  // ws layout:
  //   [0, 50331648)            att (attention output, bf16)
  //   [50331648, 100663296)    v [b,h,t,d] bf16
  //   [100663296, 101548032)   w1T [1152,384] bf16
  //   [101548032, 101842944)   pT  [384,384]  bf16
  char* ws = (char*)d_ws;
  u16* att  = (u16*)ws;
  u16* vbuf = (u16*)(ws + 50331648);
  u16* w1T  = (u16*)(ws + 100663296);
  u16* pT   = (u16*)(ws + 101548032);
  u16* qbuf = (u16*)d_out;                         // d_out doubles as q+k scratch
  u16* kbuf = (u16*)((char*)d_out + 50331648);

  transpose_cvt_k<<<dim3(1152 / 32, 384 / 32), dim3(32, 8), 0, stream>>>(qkv_w, w1T, 384, 1152);
  transpose_cvt_k<<<dim3(384 / 32, 384 / 32), dim3(32, 8), 0, stream>>>(proj_w, pT, 384, 384);

  gemm_k<1><<<1024, 128, 0, stream>>>(x, w1T, qkv_b, qbuf, kbuf, vbuf, nullptr);
  attn_k<<<256 * 6 * 4, 256, 0, stream>>>(qbuf, kbuf, vbuf, gate, att);
  gemm_k<2><<<1024, 128, 0, stream>>>(att, pT, proj_b, nullptr, nullptr, nullptr, out);
}

// Round 10
// 198.566 us; speedup vs baseline: 1.0759x; 1.0759x over previous
//
#include <hip/hip_runtime.h>
#include <hip/hip_bf16.h>

typedef unsigned short u16;
typedef __attribute__((ext_vector_type(8))) short short8;
typedef __attribute__((ext_vector_type(8))) unsigned short ushort8;
typedef __attribute__((ext_vector_type(4))) float f32x4;
typedef __attribute__((ext_vector_type(4))) float f4;

#define GLB_CAST(p) ((const __attribute__((address_space(1))) unsigned int*)(p))
#define LDS_CAST(p) ((__attribute__((address_space(3))) unsigned int*)(p))

__device__ __forceinline__ void gl_lds16(const void* g, void* l) {
  __builtin_amdgcn_global_load_lds(GLB_CAST(g), LDS_CAST(l), 16, 0, 0);
}

__device__ __forceinline__ u16 f2bf(float f) {
  __hip_bfloat16 b = __float2bfloat16(f);           // RNE
  return __builtin_bit_cast(u16, b);
}

// ---------------- prep: W [R][C] f32 -> Wt [C][R] bf16 ----------------
__global__ void transpose_cvt_k(const float* __restrict__ in,
                                u16* __restrict__ out, int R, int C) {
  __shared__ float tile[32][33];
  int c0 = blockIdx.x * 32, r0 = blockIdx.y * 32;
  int tx = threadIdx.x, ty = threadIdx.y;     // 32 x 8
#pragma unroll
  for (int i = 0; i < 32; i += 8)
    tile[ty + i][tx] = in[(size_t)(r0 + ty + i) * C + c0 + tx];
  __syncthreads();
#pragma unroll
  for (int i = 0; i < 32; i += 8)
    out[(size_t)(c0 + ty + i) * R + r0 + tx] = f2bf(tile[tx][ty + i]);
}

// ========== m97-point GEMM: 128x128 tile, BK=64, single-buffered 32KB LDS, 3 blk/CU ==========
// EPI=1: qkv = x(f32)@w1T^T (+bias) -> q/k row-major [b,h,t,d] + vT [b,h,d,t], bf16.
// EPI=2: out = att(bf16)@pT^T (+bias) -> f32 [M,384].
// 256 thr = 4 waves (2x2), wave tile 64m x 64n, acc[4][4]. Two barriers per K-step.
// A (EPI=1): f32 global->reg->bf16->swizzled ds_write; A (EPI=2) & B: global_load_lds
// with inverse-swizzled source. XCD-bijective grid swizzle (grid % 8 == 0).
template <int EPI>
__global__ __launch_bounds__(256, 3) void gemm_k(
    const void* __restrict__ Av, const u16* __restrict__ Bt,
    const float* __restrict__ bias,
    u16* __restrict__ oQ, u16* __restrict__ oK, u16* __restrict__ oVT,
    float* __restrict__ oF) {
  constexpr int K = 384;
  constexpr int NTN = (EPI == 1) ? 9 : 3;
  __shared__ u16 lA[128 * 64];   // 16KB, 128B rows, XOR-swizzled
  __shared__ u16 lB[128 * 64];   // 16KB

  const int tid = threadIdx.x;
  const int per = gridDim.x >> 3;
  const int idx = (blockIdx.x & 7) * per + (blockIdx.x >> 3);
  const int m0 = (idx / NTN) * 128;
  const int n0 = (idx % NTN) * 128;
  const int lane = tid & 63, wid = tid >> 6;
  const int lo = lane & 15, hi = lane >> 4;
  const int wr = wid >> 1, wc = wid & 1;

  // ---- staging coords (thread-constant) ----
  const int rb = tid >> 3;                  // base row; +32 per it
  const int cb = tid & 7;                   // col chunk
  const int csb = cb ^ (rb & 7);            // inverse-swizzled source chunk
  const int akey = (rb & 7) << 4;

  const float* pxa[4];                      // EPI=1: f32 A sources
  const u16* pab[4];                        // EPI=2: bf16 A sources
  const u16* pxb[4];                        // B sources
  int awoff[4];
#pragma unroll
  for (int it = 0; it < 4; ++it) {
    int r = rb + it * 32;
    if (EPI == 1) pxa[it] = (const float*)Av + (size_t)(m0 + r) * K + cb * 8;
    else          pab[it] = (const u16*)Av + (size_t)(m0 + r) * K + csb * 8;
    pxb[it] = Bt + (size_t)(n0 + r) * K + csb * 8;
    awoff[it] = r * 128 + ((cb * 16) ^ akey);
  }

  f4 xa[4][2];
  auto loadA = [&](int kt) {                // EPI=1 only
#pragma unroll
    for (int it = 0; it < 4; ++it) {
      xa[it][0] = *(const f4*)(pxa[it] + kt);
      xa[it][1] = *(const f4*)(pxa[it] + kt + 4);
    }
  };
  auto writeA = [&]() {
#pragma unroll
    for (int it = 0; it < 4; ++it) {
      ushort8 o;
#pragma unroll
      for (int j = 0; j < 4; ++j) { o[j] = f2bf(xa[it][0][j]); o[4 + j] = f2bf(xa[it][1][j]); }
      *(ushort8*)((char*)lA + awoff[it]) = o;
    }
  };
  auto stageA = [&](int kt) {               // EPI=2 only
#pragma unroll
    for (int it = 0; it < 4; ++it)
      gl_lds16(pab[it] + kt, (char*)lA + tid * 16 + it * 4096);
  };
  auto stageB = [&](int kt) {
#pragma unroll
    for (int it = 0; it < 4; ++it)
      gl_lds16(pxb[it] + kt, (char*)lB + tid * 16 + it * 4096);
  };

  const f32x4 Z4 = {0.f, 0.f, 0.f, 0.f};
  f32x4 acc[4][4];
#pragma unroll
  for (int m = 0; m < 4; ++m)
#pragma unroll
    for (int n = 0; n < 4; ++n) acc[m][n] = Z4;

  // read-side thread-constant pieces (R2-proven conflict-free)
  const int rkey = (lo & 7) << 4;
  const int arow = (wr * 64 + lo) * 128;    // + m*2048
  const int brow = (wc * 64 + lo) * 128;    // + n*2048

  // ---- prologue ----
  if (EPI == 1) {
    loadA(0);
    stageB(0);
    writeA();
    loadA(64);                              // prefetch tile 1 into regs
  } else {
    stageA(0);
    stageB(0);
  }
  __syncthreads();                          // drains vmcnt + lgkm: tile 0 ready

  for (int t = 0; t < 6; ++t) {
#pragma unroll
    for (int s = 0; s < 2; ++s) {
      const int so = (s * 64 + hi * 16) ^ rkey;
      short8 af[4], bf[4];
#pragma unroll
      for (int m = 0; m < 4; ++m) af[m] = *(const short8*)((const char*)lA + arow + m * 2048 + so);
#pragma unroll
      for (int n = 0; n < 4; ++n) bf[n] = *(const short8*)((const char*)lB + brow + n * 2048 + so);
#pragma unroll
      for (int m = 0; m < 4; ++m)
#pragma unroll
        for (int n = 0; n < 4; ++n)
          acc[m][n] = __builtin_amdgcn_mfma_f32_16x16x32_bf16(af[m], bf[n], acc[m][n], 0, 0, 0);
    }
    __syncthreads();                        // everyone done reading tile t
    if (t < 5) {
      stageB((t + 1) * 64);
      if (EPI == 1) {
        writeA();                           // xa holds tile t+1
        if (t < 4) loadA((t + 2) * 64);     // HBM latency hidden under next compute
      } else {
        stageA((t + 1) * 64);
      }
      __syncthreads();                      // vmcnt(0)+lgkm(0) drain: tile t+1 ready
    }
  }

  // ---- epilogue: direct scalar stores (R8-proven exact WRITE) ----
  float bs[4];
#pragma unroll
  for (int n = 0; n < 4; ++n) bs[n] = bias[n0 + wc * 64 + n * 16 + lo];

  if (EPI == 2) {
#pragma unroll
    for (int m = 0; m < 4; ++m)
#pragma unroll
      for (int rr = 0; rr < 4; ++rr) {
        int gm = m0 + wr * 64 + m * 16 + hi * 4 + rr;
#pragma unroll
        for (int n = 0; n < 4; ++n)
          oF[(size_t)gm * 384 + n0 + wc * 64 + n * 16 + lo] = acc[m][n][rr] + bs[n];
      }
    return;
  }

  const int region = n0 / 384;              // block lies entirely in one region
  const int nb = n0 % 384;
  // row parts: q/k -> b*98304 + t*64 ; vT -> b*98304 + t
  int rqk[4][4], rv[4][4];
#pragma unroll
  for (int m = 0; m < 4; ++m)
#pragma unroll
    for (int rr = 0; rr < 4; ++rr) {
      int gm = m0 + wr * 64 + m * 16 + hi * 4 + rr;
      int b = gm >> 8, tt = gm & 255;
      rqk[m][rr] = b * 98304 + tt * 64;
      rv[m][rr] = b * 98304 + tt;
    }
  if (region < 2) {
    u16* dst = region ? oK : oQ;
#pragma unroll
    for (int n = 0; n < 4; ++n) {
      int hc = nb + wc * 64 + n * 16 + lo;
      int cp = ((hc >> 6) << 14) + (hc & 63);         // hh*16384 + d
#pragma unroll
      for (int m = 0; m < 4; ++m)
#pragma unroll
        for (int rr = 0; rr < 4; ++rr)
          dst[(size_t)(rqk[m][rr] + cp)] = f2bf(acc[m][n][rr] + bs[n]);
    }
  } else {
#pragma unroll
    for (int n = 0; n < 4; ++n) {
      int hc = nb + wc * 64 + n * 16 + lo;
      int cp = ((hc >> 6) << 14) + (hc & 63) * 256;   // hh*16384 + d*256
#pragma unroll
      for (int m = 0; m < 4; ++m)
#pragma unroll
        for (int rr = 0; rr < 4; ++rr)
          oVT[(size_t)(rv[m][rr] + cp)] = f2bf(acc[m][n][rr] + bs[n]);
    }
  }
}

// ---------------- windowed causal attention (R2-proven: K and V^T staged via gl_lds) ----------------
__global__ __launch_bounds__(256) void attn_k(
    const u16* __restrict__ Qb, const u16* __restrict__ Kb,
    const u16* __restrict__ VTb, const float* __restrict__ gate,
    u16* __restrict__ Ao) {
  __shared__ u16 Ks[128 * 64];      // [key][d]   swizzled, 16KB
  __shared__ u16 Vs[64 * 128];      // [d][key]   swizzled, 16KB
  __shared__ u16 Ps[4][16 * 128];   // per-wave P [q][key] swizzled, 16KB
  const int bx = blockIdx.x;
  const int qt = bx & 3, bh = bx >> 2;
  const int h = bh % 6, b = bh / 6;
  const int i0 = qt * 64, j0 = i0 - 64;
  const int tid = threadIdx.x, w = tid >> 6, lane = tid & 63;
  const int lo = lane & 15, hi = lane >> 4;

  const u16* Kh = Kb + (size_t)bh * (256 * 64);
  const u16* Vh = VTb + (size_t)bh * (64 * 256);
  const u16* Qh = Qb + (size_t)bh * (256 * 64);

  // stage K [128 x 64]
#pragma unroll
  for (int it = 0; it < 4; ++it) {
    int chunk = tid + it * 256;
    int row = chunk >> 3, cc = chunk & 7;
    int csrc = cc ^ (row & 7);
    int j = j0 + row; if (j < 0) j = 0;       // masked later via P=0
    gl_lds16(Kh + j * 64 + csrc * 8, Ks + chunk * 8);
  }
  // stage V^T [64 x 128]
#pragma unroll
  for (int it = 0; it < 4; ++it) {
    int chunk = tid + it * 256;
    int d = chunk >> 4, kc = chunk & 15;
    int ksrc = kc ^ (d & 7);
    int j = j0 + ksrc * 8; if (j < 0) j = 0;  // whole-chunk invalid only
    gl_lds16(Vh + d * 256 + j, Vs + chunk * 8);
  }

  const int iq = i0 + w * 16 + lo;
  short8 aq0 = *(const short8*)(Qh + iq * 64 + hi * 8);
  short8 aq1 = *(const short8*)(Qh + iq * 64 + 32 + hi * 8);

  __syncthreads();

  const f32x4 Z4 = {0.f, 0.f, 0.f, 0.f};
  f32x4 accS[8];
#pragma unroll
  for (int t = 0; t < 8; ++t) accS[t] = Z4;
#pragma unroll
  for (int t = 0; t < 8; ++t) {
    int key = t * 16 + lo;
    int base = key * 128;
    int sw = (key & 7) << 4;
    short8 bk0 = *(const short8*)((const char*)Ks + ((base + hi * 16) ^ sw));
    short8 bk1 = *(const short8*)((const char*)Ks + ((base + 64 + hi * 16) ^ sw));
    accS[t] = __builtin_amdgcn_mfma_f32_16x16x32_bf16(aq0, bk0, accS[t], 0, 0, 0);
    accS[t] = __builtin_amdgcn_mfma_f32_16x16x32_bf16(aq1, bk1, accS[t], 0, 0, 0);
  }

  float pv[4][8];
  float rinv[4];
#pragma unroll
  for (int r = 0; r < 4; ++r) {
    int i = i0 + w * 16 + hi * 4 + r;
    float mx = -1e30f;
    float vals[8];
#pragma unroll
    for (int t = 0; t < 8; ++t) {
      int j = j0 + t * 16 + lo;
      float s = accS[t][r] * 0.125f;          // 1/sqrt(64)
      bool ok = (j >= 0) && (j <= i) && (j >= i - 64);
      vals[t] = ok ? s : -1e30f;
      mx = fmaxf(mx, vals[t]);
    }
#pragma unroll
    for (int off = 1; off < 16; off <<= 1) mx = fmaxf(mx, __shfl_xor(mx, off));
    float sum = 0.f;
#pragma unroll
    for (int t = 0; t < 8; ++t) {
      float p = __expf(vals[t] - mx);
      pv[r][t] = p;
      sum += p;
    }
#pragma unroll
    for (int off = 1; off < 16; off <<= 1) sum += __shfl_xor(sum, off);
    rinv[r] = 1.0f / sum;
  }

  u16* Pw = Ps[w];
#pragma unroll
  for (int r = 0; r < 4; ++r) {
    int ql = hi * 4 + r;
    int sw = (ql & 7) << 4;
#pragma unroll
    for (int t = 0; t < 8; ++t) {
      int off = (ql * 256 + (t * 16 + lo) * 2) ^ sw;
      *(u16*)((char*)Pw + off) = f2bf(pv[r][t]);
    }
  }

  f32x4 accO[4];
#pragma unroll
  for (int dt = 0; dt < 4; ++dt) accO[dt] = Z4;
#pragma unroll
  for (int ks = 0; ks < 4; ++ks) {
    int offA = (lo * 256 + ks * 64 + hi * 16) ^ ((lo & 7) << 4);
    short8 ap = *(const short8*)((const char*)Pw + offA);
#pragma unroll
    for (int dt = 0; dt < 4; ++dt) {
      int d = dt * 16 + lo;
      int offB = (d * 256 + ks * 64 + hi * 16) ^ ((d & 7) << 4);
      short8 bv = *(const short8*)((const char*)Vs + offB);
      accO[dt] = __builtin_amdgcn_mfma_f32_16x16x32_bf16(ap, bv, accO[dt], 0, 0, 0);
    }
  }

#pragma unroll
  for (int dt = 0; dt < 4; ++dt) {
    int d = dt * 16 + lo;
    float gg = gate[h * 64 + d];
#pragma unroll
    for (int r = 0; r < 4; ++r) {
      int i = i0 + w * 16 + hi * 4 + r;
      float v = accO[dt][r] * rinv[r] * gg;
      Ao[(size_t)(b * 256 + i) * 384 + h * 64 + d] = f2bf(v);
    }
  }
}

// ---------------- launch ----------------
extern "C" void kernel_launch(void* const* d_in, const int* in_sizes, int n_in,
                              void* d_out, int out_size, void* d_ws, size_t ws_size,
                              hipStream_t stream) {
  const float* x      = (const float*)d_in[0];
  const float* qkv_w  = (const float*)d_in[1];
  const float* qkv_b  = (const float*)d_in[2];
  const float* proj_w = (const float*)d_in[3];
  const float* proj_b = (const float*)d_in[4];
  const float* gate   = (const float*)d_in[5];
  float* out = (float*)d_out;

  // ws layout:
  //   [0, 50331648)            att (attention output, bf16)
  //   [50331648, 100663296)    vT [b,h,d,t] bf16
  //   [100663296, 101548032)   w1T [1152,384] bf16
  //   [101548032, 101842944)   pT  [384,384]  bf16
  char* ws = (char*)d_ws;
  u16* att  = (u16*)ws;
  u16* vT   = (u16*)(ws + 50331648);
  u16* w1T  = (u16*)(ws + 100663296);
  u16* pT   = (u16*)(ws + 101548032);
  u16* qbuf = (u16*)d_out;                         // d_out doubles as q+k scratch
  u16* kbuf = (u16*)((char*)d_out + 50331648);

  transpose_cvt_k<<<dim3(1152 / 32, 384 / 32), dim3(32, 8), 0, stream>>>(qkv_w, w1T, 384, 1152);
  transpose_cvt_k<<<dim3(384 / 32, 384 / 32), dim3(32, 8), 0, stream>>>(proj_w, pT, 384, 384);

  gemm_k<1><<<4608, 256, 0, stream>>>(x, w1T, qkv_b, qbuf, kbuf, vT, nullptr);
  attn_k<<<256 * 6 * 4, 256, 0, stream>>>(qbuf, kbuf, vT, gate, att);
  gemm_k<2><<<1536, 256, 0, stream>>>(att, pT, proj_b, nullptr, nullptr, nullptr, out);
}